// Round 10
// baseline (1070.337 us; speedup 1.0000x reference)
//
#include <hip/hip_runtime.h>
#include <hip/hip_bf16.h>
#include <hip/hip_fp16.h>

typedef unsigned short u16;
typedef unsigned char u8;
typedef unsigned int u32;
typedef __attribute__((ext_vector_type(8))) short short8;
typedef __attribute__((ext_vector_type(4))) float f32x4;
typedef __attribute__((ext_vector_type(2))) _Float16 half2_t;

#define B_ 64
#define T_ 512
#define E_ 300
#define KP_ 320
#define H_ 128
#define G_ 512
#define C_ 20
#define NCH_ 32
#define CS_ 16

__device__ __forceinline__ float b2f(u16 u) {
    union { u32 i; float f; } v; v.i = ((u32)u) << 16; return v.f;
}
__device__ __forceinline__ u16 f2b(float f) {
    union { float f; u32 i; } v; v.f = f;
    u32 r = (v.i + 0x7fffu + ((v.i >> 16) & 1u)) >> 16;   // RNE
    return (u16)r;
}
__device__ __forceinline__ float loadf(const void* p, long i, u32 isf32) {
    return isf32 ? ((const float*)p)[i] : b2f(((const u16*)p)[i]);
}
__device__ __forceinline__ float sigmoidf_(float x) {
    return 1.0f / (1.0f + __expf(-x));
}
__device__ __forceinline__ float tanhf_(float x) {
    float cx = fminf(fmaxf(x, -15.f), 15.f);
    float e = __expf(2.f * cx);
    return (e - 1.f) / (e + 1.f);
}
__device__ __forceinline__ int loadmask(const void* m, int idx, u32 isbool) {
    return isbool ? (int)((const u8*)m)[idx] : ((const int*)m)[idx];
}
__device__ __forceinline__ u16 f2h(float f) {
    __half h = __float2half(f);
    return __half_as_ushort(h);
}
// packed f16x2 dot-accumulate: a.x*b.x + a.y*b.y + c (one v_dot2 inst)
__device__ __forceinline__ float dot2f(u32 a, u32 b, float c) {
#if __has_builtin(__builtin_amdgcn_fdot2)
    return __builtin_amdgcn_fdot2(__builtin_bit_cast(half2_t, a),
                                  __builtin_bit_cast(half2_t, b), c, false);
#else
    half2_t av = __builtin_bit_cast(half2_t, a);
    half2_t bv = __builtin_bit_cast(half2_t, b);
    return c + (float)av.x * (float)bv.x + (float)av.y * (float)bv.y;
#endif
}

// ---------------- sniff input dtypes (deterministic, same result every call)
__global__ void sniff_kernel(const u32* __restrict__ emb32,
                             const u32* __restrict__ mask32,
                             u32* __restrict__ flags) {
    if (threadIdx.x == 0) {
        u32 nz = 0;
        for (int i = 150; i < 300; ++i) nz |= emb32[i];
        flags[0] = (nz == 0) ? 1u : 0u;          // f32 floats?
        u32 m0 = mask32[0];
        flags[1] = ((m0 & 0xFFFFFF00u) != 0) ? 1u : 0u;  // bool mask?
    }
}

// ---------------- prep: normalize weights into canonical buffers
__global__ __launch_bounds__(256) void prep_kernel(
    const void* __restrict__ Wihf, const void* __restrict__ Wihb,
    const void* __restrict__ Whhf, const void* __restrict__ Whhb,
    const void* __restrict__ bihf, const void* __restrict__ bhhf,
    const void* __restrict__ bihb, const void* __restrict__ bhhb,
    const void* __restrict__ fcW, const void* __restrict__ fcb,
    const void* __restrict__ trans, const u32* __restrict__ flags,
    u16* __restrict__ Wpad, u32* __restrict__ Whh2, float* __restrict__ biasc,
    u16* __restrict__ fcWc, float* __restrict__ fcbf, float* __restrict__ transf) {
    const u32 isf32 = flags[0];
    int idx = blockIdx.x * 256 + threadIdx.x;
    if (idx < 2 * G_ * KP_) {
        int dir = idx / (G_ * KP_), rem = idx % (G_ * KP_);
        int g = rem / KP_, kp = rem % KP_;
        const void* src = dir ? Wihb : Wihf;
        float v = (kp < E_) ? loadf(src, (long)g * E_ + kp, isf32) : 0.f;
        Wpad[idx] = f2b(v);
        return;
    }
    idx -= 2 * G_ * KP_;
    if (idx < 2 * G_ * 64) {
        int dir = idx >> 15, rem = idx & 32767;
        int row = rem >> 6, k2 = rem & 63;
        const void* src = dir ? Whhb : Whhf;
        float w0 = loadf(src, (long)row * H_ + 2 * k2, isf32);
        float w1 = loadf(src, (long)row * H_ + 2 * k2 + 1, isf32);
        Whh2[idx] = (u32)f2h(w0) | ((u32)f2h(w1) << 16);
        return;
    }
    idx -= 2 * G_ * 64;
    if (idx < 2 * G_) {
        int dir = idx >> 9, g = idx & 511;
        biasc[idx] = loadf(dir ? bihb : bihf, g, isf32) +
                     loadf(dir ? bhhb : bhhf, g, isf32);
        return;
    }
    idx -= 2 * G_;
    if (idx < C_ * 256) { fcWc[idx] = f2b(loadf(fcW, idx, isf32)); return; }
    idx -= C_ * 256;
    if (idx < C_) { fcbf[idx] = loadf(fcb, idx, isf32); return; }
    idx -= C_;
    if (idx < C_ * C_) { transf[idx] = loadf(trans, idx, isf32); return; }
}

// ---------------- chunked xw GEMM with fused embedding gather (dtype-adaptive A).
// Epilogue interleaves columns: original gate index n -> ((n&127)<<2)|(n>>7)
// so the LSTM reads its 4 gates of unit j as one dwordx2 at column 4j.
__global__ __launch_bounds__(256) void gemm_xw(const int* __restrict__ x,
                                               const void* __restrict__ emb,
                                               const u16* __restrict__ Wpad,
                                               const float* __restrict__ biasc,
                                               const u32* __restrict__ flags,
                                               u16* __restrict__ xwf, u16* __restrict__ xwb,
                                               int tclog2, int t0f, int t0b) {
    const int m0 = blockIdx.x * 128;
    const int n0 = blockIdx.y * 128;
    const int dir = blockIdx.z;
    const u16* Bw = Wpad + (size_t)dir * G_ * KP_;
    u16* out = dir ? xwb : xwf;
    const int t0 = dir ? t0b : t0f;
    const int ts = dir ? -1 : 1;
    const int tcm = (1 << tclog2) - 1;
    const u32 isf32 = flags[0];

    __shared__ __align__(16) short As[128 * 32];
    __shared__ __align__(16) short Bs[128 * 32];
    __shared__ int xs[128];

    const int tid = threadIdx.x;
    const int lane = tid & 63;
    const int wave = tid >> 6;
    const int wm = wave & 1, wn = wave >> 1;
    const int lr = lane & 15, lq = lane >> 4;

    if (tid < 128) {
        int i = m0 + tid;
        int b = i >> tclog2;
        int r = i & tcm;
        xs[tid] = x[b * T_ + t0 + ts * r];
    }
    __syncthreads();

    f32x4 acc[4][4];
#pragma unroll
    for (int mt = 0; mt < 4; ++mt)
#pragma unroll
        for (int nt = 0; nt < 4; ++nt)
            acc[mt][nt] = (f32x4){0.f, 0.f, 0.f, 0.f};

    for (int kb = 0; kb < KP_; kb += 32) {
        if (isf32) {
            const float* ef = (const float*)emb;
#pragma unroll
            for (int hh = 0; hh < 4; ++hh) {
                int c = tid + hh * 256;
                int row = c >> 3;
                int k4 = (c & 7) * 4;
                int k = kb + k4;
                uint2 o = make_uint2(0u, 0u);
                if (k < E_) {
                    float4 v = *(const float4*)(ef + (size_t)xs[row] * E_ + k);
                    o.x = (u32)f2b(v.x) | ((u32)f2b(v.y) << 16);
                    o.y = (u32)f2b(v.z) | ((u32)f2b(v.w) << 16);
                }
                *(uint2*)(&As[row * 32 + k4]) = o;
            }
        } else {
            const u16* eb = (const u16*)emb;
#pragma unroll
            for (int hh = 0; hh < 4; ++hh) {
                int c = tid + hh * 256;
                int row = c >> 3;
                int k4 = (c & 7) * 4;
                int k = kb + k4;
                uint2 va = make_uint2(0u, 0u);
                if (k < E_)
                    va = *(const uint2*)(eb + (size_t)xs[row] * E_ + k);
                *(uint2*)(&As[row * 32 + k4]) = va;
            }
        }
#pragma unroll
        for (int hh = 0; hh < 2; ++hh) {
            int c = tid + hh * 256;
            int row = c >> 2;
            int k8 = (c & 3) * 8;
            uint4 vb = *(const uint4*)(Bw + (size_t)(n0 + row) * KP_ + kb + k8);
            *(uint4*)(&Bs[row * 32 + k8]) = vb;
        }
        __syncthreads();
        short8 afr[4], bfr[4];
#pragma unroll
        for (int mt = 0; mt < 4; ++mt)
            afr[mt] = *(const short8*)&As[(wm * 64 + mt * 16 + lr) * 32 + lq * 8];
#pragma unroll
        for (int nt = 0; nt < 4; ++nt)
            bfr[nt] = *(const short8*)&Bs[(wn * 64 + nt * 16 + lr) * 32 + lq * 8];
#pragma unroll
        for (int mt = 0; mt < 4; ++mt)
#pragma unroll
            for (int nt = 0; nt < 4; ++nt)
                acc[mt][nt] = __builtin_amdgcn_mfma_f32_16x16x32_bf16(afr[mt], bfr[nt], acc[mt][nt], 0, 0, 0);
        __syncthreads();
    }
#pragma unroll
    for (int nt = 0; nt < 4; ++nt) {
        int n = n0 + wn * 64 + nt * 16 + lr;
        float bn = biasc[dir * G_ + n];
        int np = ((n & 127) << 2) | (n >> 7);    // interleaved [unit][gate]
#pragma unroll
        for (int mt = 0; mt < 4; ++mt) {
            int mbase = m0 + wm * 64 + mt * 16 + lq * 4;
#pragma unroll
            for (int r = 0; r < 4; ++r)
                out[(size_t)(mbase + r) * G_ + np] = f2b(acc[mt][nt][r] + bn);
        }
    }
}

// ---------------- LSTM recurrence: one block per (b, dir), 128 threads.
// Thread j owns ALL FOUR gates of unit j: 4 W rows (256 VGPRs via inline-asm
// loads, waves_per_eu(1,1) -> 512 VGPR budget), no shuffles, 2 waves/block,
// 32 LDS b128 broadcasts per CU per step (4x fewer than r9), 1 barrier/step.
#define DOTQ4(acc, wq, hq) \
    acc = dot2f(wq.x, hq.x, acc); acc = dot2f(wq.y, hq.y, acc); \
    acc = dot2f(wq.z, hq.z, acc); acc = dot2f(wq.w, hq.w, acc);

#define GLD(dst, ptr, OFF) \
    asm volatile("global_load_dwordx4 %0, %1, off offset:" OFF : "=v"(dst) : "v"(ptr))

#define STEP_I(n) { uint4 hq = hp[n]; \
    DOTQ4(aI, wi##n, hq) DOTQ4(aF, wf##n, hq) \
    DOTQ4(aG, wg##n, hq) DOTQ4(aO, wo##n, hq) }

__global__ __launch_bounds__(128)
__attribute__((amdgpu_waves_per_eu(1, 1)))
void lstm_kernel(const u32* __restrict__ Whh2,
                 const u16* __restrict__ xwf,
                 const u16* __restrict__ xwb,
                 u16* __restrict__ hf,
                 u16* __restrict__ hb,
                 float* __restrict__ carry,
                 int TC, int t0f, int t0b, int first) {
    const int b = blockIdx.x;
    const int dir = blockIdx.y;
    const int j = threadIdx.x;                   // unit index 0..127
    const u16* xw = (dir ? xwb : xwf) + (size_t)b * TC * G_ + 4 * j;
    u16* hout = (dir ? hb : hf) + (size_t)b * T_ * H_;
    const int t0 = dir ? t0b : t0f;
    const int ts = dir ? -1 : 1;
    float* carry_c = carry + (size_t)(dir * B_ + b) * H_;
    float* carry_h = carry + (size_t)(2 * B_ + dir * B_ + b) * H_;

    const u32* Wbase = Whh2 + (size_t)dir * G_ * 64;
    const uint4* WI = (const uint4*)(Wbase + (size_t)(0 + j) * 64);
    const uint4* WF = (const uint4*)(Wbase + (size_t)(128 + j) * 64);
    const uint4* WG = (const uint4*)(Wbase + (size_t)(256 + j) * 64);
    const uint4* WO = (const uint4*)(Wbase + (size_t)(384 + j) * 64);

    uint4 wi0, wi1, wi2, wi3, wi4, wi5, wi6, wi7, wi8, wi9, wi10, wi11, wi12, wi13, wi14, wi15;
    uint4 wf0, wf1, wf2, wf3, wf4, wf5, wf6, wf7, wf8, wf9, wf10, wf11, wf12, wf13, wf14, wf15;
    uint4 wg0, wg1, wg2, wg3, wg4, wg5, wg6, wg7, wg8, wg9, wg10, wg11, wg12, wg13, wg14, wg15;
    uint4 wo0, wo1, wo2, wo3, wo4, wo5, wo6, wo7, wo8, wo9, wo10, wo11, wo12, wo13, wo14, wo15;
    GLD(wi0, WI, "0");    GLD(wi1, WI, "16");   GLD(wi2, WI, "32");   GLD(wi3, WI, "48");
    GLD(wi4, WI, "64");   GLD(wi5, WI, "80");   GLD(wi6, WI, "96");   GLD(wi7, WI, "112");
    GLD(wi8, WI, "128");  GLD(wi9, WI, "144");  GLD(wi10, WI, "160"); GLD(wi11, WI, "176");
    GLD(wi12, WI, "192"); GLD(wi13, WI, "208"); GLD(wi14, WI, "224"); GLD(wi15, WI, "240");
    GLD(wf0, WF, "0");    GLD(wf1, WF, "16");   GLD(wf2, WF, "32");   GLD(wf3, WF, "48");
    GLD(wf4, WF, "64");   GLD(wf5, WF, "80");   GLD(wf6, WF, "96");   GLD(wf7, WF, "112");
    GLD(wf8, WF, "128");  GLD(wf9, WF, "144");  GLD(wf10, WF, "160"); GLD(wf11, WF, "176");
    GLD(wf12, WF, "192"); GLD(wf13, WF, "208"); GLD(wf14, WF, "224"); GLD(wf15, WF, "240");
    GLD(wg0, WG, "0");    GLD(wg1, WG, "16");   GLD(wg2, WG, "32");   GLD(wg3, WG, "48");
    GLD(wg4, WG, "64");   GLD(wg5, WG, "80");   GLD(wg6, WG, "96");   GLD(wg7, WG, "112");
    GLD(wg8, WG, "128");  GLD(wg9, WG, "144");  GLD(wg10, WG, "160"); GLD(wg11, WG, "176");
    GLD(wg12, WG, "192"); GLD(wg13, WG, "208"); GLD(wg14, WG, "224"); GLD(wg15, WG, "240");
    GLD(wo0, WO, "0");    GLD(wo1, WO, "16");   GLD(wo2, WO, "32");   GLD(wo3, WO, "48");
    GLD(wo4, WO, "64");   GLD(wo5, WO, "80");   GLD(wo6, WO, "96");   GLD(wo7, WO, "112");
    GLD(wo8, WO, "128");  GLD(wo9, WO, "144");  GLD(wo10, WO, "160"); GLD(wo11, WO, "176");
    GLD(wo12, WO, "192"); GLD(wo13, WO, "208"); GLD(wo14, WO, "224"); GLD(wo15, WO, "240");
    asm volatile("s_waitcnt vmcnt(0)" ::: "memory");

    __shared__ __align__(16) u16 hs2[2][H_];     // h as f16, 256 B per buffer

    float c0 = first ? 0.f : carry_c[j];
    hs2[0][j] = first ? (u16)0 : f2h(carry_h[j]);
    __syncthreads();

    int cur = 0;
    uint2 xq  = *(const uint2*)(xw);
    uint2 xq1 = (TC > 1) ? *(const uint2*)(xw + (size_t)1 * G_) : make_uint2(0u, 0u);
    float hlast = 0.f;
    for (int r = 0; r < TC; ++r) {
        uint2 xq2 = make_uint2(0u, 0u);
        if (r + 2 < TC) xq2 = *(const uint2*)(xw + (size_t)(r + 2) * G_);  // 2-deep prefetch
        const uint4* hp = (const uint4*)hs2[cur];
        float aI = 0.f, aF = 0.f, aG = 0.f, aO = 0.f;
        STEP_I(0)  STEP_I(1)  STEP_I(2)  STEP_I(3)
        STEP_I(4)  STEP_I(5)  STEP_I(6)  STEP_I(7)
        STEP_I(8)  STEP_I(9)  STEP_I(10) STEP_I(11)
        STEP_I(12) STEP_I(13) STEP_I(14) STEP_I(15)
        float gi = sigmoidf_(b2f((u16)(xq.x & 0xffff)) + aI);
        float gf = sigmoidf_(b2f((u16)(xq.x >> 16)) + aF);
        float gg = tanhf_(b2f((u16)(xq.y & 0xffff)) + aG);
        float go = sigmoidf_(b2f((u16)(xq.y >> 16)) + aO);
        c0 = gf * c0 + gi * gg;
        float h = go * tanhf_(c0);
        hlast = h;
        hs2[cur ^ 1][j] = f2h(h);
        hout[(size_t)(t0 + ts * r) * H_ + j] = f2b(h);
        __syncthreads();
        cur ^= 1;
        xq = xq1; xq1 = xq2;
    }
    carry_c[j] = c0; carry_h[j] = hlast;
}

// ---------------- fc: logits = concat(hf,hb) @ fc_W^T + fc_b
__global__ __launch_bounds__(256) void fc_kernel(const u16* __restrict__ hf,
                                                 const u16* __restrict__ hb,
                                                 const u16* __restrict__ fcWc,
                                                 const float* __restrict__ fcbf,
                                                 const u32* __restrict__ flags,
                                                 float* __restrict__ logits,
                                                 void* __restrict__ dout) {
    __shared__ float Ws[C_ * 256];
    __shared__ float Hs[16 * 256];
    const int tid = threadIdx.x;
    const int bt0 = blockIdx.x * 64;
    const u32 isf32 = flags[0];
#pragma unroll
    for (int i = 0; i < C_; ++i) {
        int v = tid + i * 256;
        Ws[v] = b2f(fcWc[v]);
    }
    __syncthreads();
    for (int grp = 0; grp < 4; ++grp) {
        int btg = bt0 + grp * 16;
#pragma unroll
        for (int i = 0; i < 16; ++i) {
            int v = tid + i * 256;
            int r = v >> 8, k = v & 255;
            Hs[v] = (k < H_) ? b2f(hf[(size_t)(btg + r) * H_ + k])
                             : b2f(hb[(size_t)(btg + r) * H_ + (k - H_)]);
        }
        __syncthreads();
#pragma unroll
        for (int q = 0; q < 2; ++q) {
            int p = tid + q * 256;
            if (p < 16 * C_) {
                int r = p / C_, cc = p % C_;
                float acc = fcbf[cc];
                const float* wr = &Ws[cc * 256];
                const float* hr = &Hs[r * 256];
#pragma unroll
                for (int k = 0; k < 256; k += 4)
                    acc += wr[k] * hr[k] + wr[k + 1] * hr[k + 1] +
                           wr[k + 2] * hr[k + 2] + wr[k + 3] * hr[k + 3];
                size_t o = (size_t)(btg + r) * C_ + cc;
                logits[o] = acc;
                if (isf32) ((float*)dout)[1 + o] = acc;
                else       ((u16*)dout)[1 + o] = f2b(acc);
            }
        }
        __syncthreads();
    }
}

// ---------------- CRF phase A: per-(b,chunk) semiring product of step matrices.
__global__ __launch_bounds__(512) void crf_chunk(const float* __restrict__ logits,
                                                 const void* __restrict__ mask,
                                                 const float* __restrict__ transf,
                                                 const u32* __restrict__ flags,
                                                 float* __restrict__ Mc) {
    const int c = blockIdx.x;
    const int b = blockIdx.y;
    const int p = threadIdx.x;
    const bool act = p < C_ * C_;
    const int i = p / C_, j = p % C_;
    const u32 isbool = flags[1];

    __shared__ float P[C_ * C_];
    float trj[C_];
    if (act) {
#pragma unroll
        for (int k = 0; k < C_; ++k) trj[k] = transf[k * C_ + j];
        P[p] = (i == j) ? 0.f : -1e30f;
    }
    __syncthreads();

    const float* lg = logits + (size_t)b * T_ * C_;
    const int t0 = 1 + CS_ * c;

    float e = 0.f; int mk = 0;
    if (act) e = lg[(size_t)t0 * C_ + j];
    mk = loadmask(mask, b * T_ + t0, isbool);

    for (int s = 0; s < CS_; ++s) {
        int t = t0 + s;
        if (t >= T_) break;
        float e_n = 0.f; int mk_n = 0;
        int tn = t + 1;
        if (s + 1 < CS_ && tn < T_) {
            if (act) e_n = lg[(size_t)tn * C_ + j];
            mk_n = loadmask(mask, b * T_ + tn, isbool);
        }
        float nv = 0.f;
        if (act) {
            float sv[C_];
            float mx = -3e38f;
#pragma unroll
            for (int k = 0; k < C_; ++k) {
                sv[k] = P[i * C_ + k] + trj[k];
                mx = fmaxf(mx, sv[k]);
            }
            float sum = 0.f;
#pragma unroll
            for (int k = 0; k < C_; ++k) sum += __expf(sv[k] - mx);
            float la = mx + __logf(sum) + e;
            nv = mk ? la : P[p];
        }
        __syncthreads();
        if (act) P[p] = nv;
        __syncthreads();
        e = e_n; mk = mk_n;
    }
    if (act) Mc[((size_t)b * NCH_ + c) * (C_ * C_) + p] = P[p];
}

// ---------------- CRF phase B: per-b serial combine over 32 chunk matrices.
__global__ __launch_bounds__(64) void crf_combine(const float* __restrict__ logits,
                                                  const float* __restrict__ Mc,
                                                  float* __restrict__ log_den) {
    const int b = blockIdx.x;
    const int j = threadIdx.x;
    const bool act = j < C_;
    __shared__ float alpha[C_];
    const float* lg = logits + (size_t)b * T_ * C_;
    const float* mb = Mc + (size_t)b * NCH_ * (C_ * C_);
    if (act) alpha[j] = lg[j];
    __syncthreads();

    float mc[C_], mcn[C_];
    if (act) {
#pragma unroll
        for (int i = 0; i < C_; ++i) mc[i] = mb[i * C_ + j];
    }
    for (int c = 0; c < NCH_; ++c) {
        if (act && c + 1 < NCH_) {
#pragma unroll
            for (int i = 0; i < C_; ++i) mcn[i] = mb[(size_t)(c + 1) * (C_ * C_) + i * C_ + j];
        }
        float nv = 0.f;
        if (act) {
            float sv[C_];
            float mx = -3e38f;
#pragma unroll
            for (int i = 0; i < C_; ++i) {
                sv[i] = alpha[i] + mc[i];
                mx = fmaxf(mx, sv[i]);
            }
            float sum = 0.f;
#pragma unroll
            for (int i = 0; i < C_; ++i) sum += __expf(sv[i] - mx);
            nv = mx + __logf(sum);
        }
        __syncthreads();
        if (act) alpha[j] = nv;
        __syncthreads();
#pragma unroll
        for (int i = 0; i < C_; ++i) mc[i] = mcn[i];
    }
    if (j == 0) {
        float mx = -3e38f;
#pragma unroll
        for (int i = 0; i < C_; ++i) mx = fmaxf(mx, alpha[i]);
        float sum = 0.f;
#pragma unroll
        for (int i = 0; i < C_; ++i) sum += __expf(alpha[i] - mx);
        log_den[b] = mx + __logf(sum);
    }
}

// ---------------- loss numerator: one block per b, lane-strided over t
__global__ __launch_bounds__(64) void loss_partial(const float* __restrict__ logits,
                                                   const void* __restrict__ mask,
                                                   const int* __restrict__ tags,
                                                   const float* __restrict__ transf,
                                                   const u32* __restrict__ flags,
                                                   float* __restrict__ num) {
    const int b = blockIdx.x;
    const int lane = threadIdx.x;
    const u32 isbool = flags[1];
    const float* lg = logits + (size_t)b * T_ * C_;
    const int* tg = tags + b * T_;
    float s = 0.f;
    for (int t = lane; t < T_; t += 64) {
        int tt = tg[t];
        int mm = loadmask(mask, b * T_ + t, isbool);
        if (mm) s += lg[(size_t)t * C_ + tt];
        if (t >= 1) {
            int tp = tg[t - 1];
            int mp = loadmask(mask, b * T_ + t - 1, isbool);
            if (mm && mp) s += transf[tp * C_ + tt];
        }
    }
#pragma unroll
    for (int off = 32; off >= 1; off >>= 1)
        s += __shfl_down(s, off, 64);
    if (lane == 0) num[b] = s;
}

// ---------------- final: mean(log_den - log_num) -> dout[0]
__global__ __launch_bounds__(64) void loss_final(const float* __restrict__ den,
                                                 const float* __restrict__ num,
                                                 const u32* __restrict__ flags,
                                                 void* __restrict__ dout) {
    const int b = threadIdx.x;
    float v = den[b] - num[b];
#pragma unroll
    for (int off = 32; off >= 1; off >>= 1)
        v += __shfl_down(v, off, 64);
    if (b == 0) {
        float loss = v * (1.0f / B_);
        if (flags[0]) ((float*)dout)[0] = loss;
        else          ((u16*)dout)[0] = f2b(loss);
    }
}

extern "C" void kernel_launch(void* const* d_in, const int* in_sizes, int n_in,
                              void* d_out, int out_size, void* d_ws, size_t ws_size,
                              hipStream_t stream) {
    const int* x     = (const int*)d_in[0];
    const void* mask = d_in[1];
    const int* tags  = (const int*)d_in[2];
    const void* emb  = d_in[3];
    const void* Wihf = d_in[4];
    const void* Whhf = d_in[5];
    const void* bihf = d_in[6];
    const void* bhhf = d_in[7];
    const void* Wihb = d_in[8];
    const void* Whhb = d_in[9];
    const void* bihb = d_in[10];
    const void* bhhb = d_in[11];
    const void* fcW  = d_in[12];
    const void* fcb  = d_in[13];
    const void* trans= d_in[14];

    char* ws = (char*)d_ws;
    u32*   flags = (u32*)(ws + 0);                // 256
    u16*   Wpad  = (u16*)(ws + 256);              // 655,360
    u32*   Whh2  = (u32*)(ws + 655616);           // 262,144 (f16x2 packed)
    float* biasc = (float*)(ws + 917760);         // 4,096
    u16*   fcWc  = (u16*)(ws + 921856);           // 10,240
    float* fcbf  = (float*)(ws + 932096);         // 128
    float* transf= (float*)(ws + 932224);         // 1,664
    u16*   hf    = (u16*)(ws + 933888);           // 8,388,608
    u16*   hb    = (u16*)(ws + 9322496);          // 8,388,608
    float* lgf   = (float*)(ws + 17711104);       // 2,621,440
    float* den   = (float*)(ws + 20332544);       // 256
    float* carry = (float*)(ws + 20332800);       // 131,072
    float* Mc    = (float*)(ws + 20463872);       // 3,276,800
    float* numb  = (float*)(ws + 23740672);       // 256
    const size_t xw_off = 23740928;

    int TC, lg2;
    if (ws_size >= xw_off + 2ull * 65536ull * 512ull + 4096ull)      { TC = 512; lg2 = 9; }
    else if (ws_size >= xw_off + 2ull * 65536ull * 256ull + 4096ull) { TC = 256; lg2 = 8; }
    else if (ws_size >= xw_off + 2ull * 65536ull * 128ull + 4096ull) { TC = 128; lg2 = 7; }
    else if (ws_size >= xw_off + 2ull * 65536ull * 64ull + 4096ull)  { TC = 64;  lg2 = 6; }
    else                                                             { TC = 32;  lg2 = 5; }
    u16* xwf = (u16*)(ws + xw_off);
    u16* xwb = (u16*)(ws + xw_off + (size_t)65536 * TC);

    hipLaunchKernelGGL(sniff_kernel, dim3(1), dim3(64), 0, stream,
                       (const u32*)emb, (const u32*)mask, flags);
    hipLaunchKernelGGL(prep_kernel, dim3(1562), dim3(256), 0, stream,
                       Wihf, Wihb, Whhf, Whhb, bihf, bhhf, bihb, bhhb,
                       fcW, fcb, trans, flags, Wpad, Whh2, biasc, fcWc, fcbf, transf);

    const int nc = T_ / TC;
    for (int ci = 0; ci < nc; ++ci) {
        int t0f = ci * TC;
        int t0b = T_ - 1 - ci * TC;
        hipLaunchKernelGGL(gemm_xw, dim3((B_ * TC) / 128, 4, 2), dim3(256), 0, stream,
                           x, emb, Wpad, biasc, flags, xwf, xwb, lg2, t0f, t0b);
        hipLaunchKernelGGL(lstm_kernel, dim3(B_, 2), dim3(128), 0, stream,
                           Whh2, xwf, xwb, hf, hb, carry, TC, t0f, t0b, (ci == 0) ? 1 : 0);
    }

    hipLaunchKernelGGL(fc_kernel, dim3(512), dim3(256), 0, stream,
                       hf, hb, fcWc, fcbf, flags, lgf, d_out);
    hipLaunchKernelGGL(crf_chunk, dim3(NCH_, B_), dim3(512), 0, stream,
                       lgf, mask, transf, flags, Mc);
    hipLaunchKernelGGL(crf_combine, dim3(B_), dim3(64), 0, stream, lgf, Mc, den);
    hipLaunchKernelGGL(loss_partial, dim3(B_), dim3(64), 0, stream,
                       lgf, mask, tags, transf, flags, numb);
    hipLaunchKernelGGL(loss_final, dim3(1), dim3(64), 0, stream, den, numb, flags, d_out);
}

// Round 11
// 791.276 us; speedup vs baseline: 1.3527x; 1.3527x over previous
//
#include <hip/hip_runtime.h>
#include <hip/hip_bf16.h>
#include <hip/hip_fp16.h>

typedef unsigned short u16;
typedef unsigned char u8;
typedef unsigned int u32;
typedef __attribute__((ext_vector_type(8))) short short8;
typedef __attribute__((ext_vector_type(4))) float f32x4;
typedef __attribute__((ext_vector_type(2))) _Float16 half2_t;

#define B_ 64
#define T_ 512
#define E_ 300
#define KP_ 320
#define H_ 128
#define G_ 512
#define C_ 20
#define NCH_ 32
#define CS_ 16

__device__ __forceinline__ float b2f(u16 u) {
    union { u32 i; float f; } v; v.i = ((u32)u) << 16; return v.f;
}
__device__ __forceinline__ u16 f2b(float f) {
    union { float f; u32 i; } v; v.f = f;
    u32 r = (v.i + 0x7fffu + ((v.i >> 16) & 1u)) >> 16;   // RNE
    return (u16)r;
}
__device__ __forceinline__ float loadf(const void* p, long i, u32 isf32) {
    return isf32 ? ((const float*)p)[i] : b2f(((const u16*)p)[i]);
}
__device__ __forceinline__ float sigmoidf_(float x) {
    return 1.0f / (1.0f + __expf(-x));
}
__device__ __forceinline__ float tanhf_(float x) {
    float cx = fminf(fmaxf(x, -15.f), 15.f);
    float e = __expf(2.f * cx);
    return (e - 1.f) / (e + 1.f);
}
__device__ __forceinline__ int loadmask(const void* m, int idx, u32 isbool) {
    return isbool ? (int)((const u8*)m)[idx] : ((const int*)m)[idx];
}
__device__ __forceinline__ u16 f2h(float f) {
    __half h = __float2half(f);
    return __half_as_ushort(h);
}
// packed f16x2 dot-accumulate: a.x*b.x + a.y*b.y + c (one v_dot2 inst)
__device__ __forceinline__ float dot2f(u32 a, u32 b, float c) {
#if __has_builtin(__builtin_amdgcn_fdot2)
    return __builtin_amdgcn_fdot2(__builtin_bit_cast(half2_t, a),
                                  __builtin_bit_cast(half2_t, b), c, false);
#else
    half2_t av = __builtin_bit_cast(half2_t, a);
    half2_t bv = __builtin_bit_cast(half2_t, b);
    return c + (float)av.x * (float)bv.x + (float)av.y * (float)bv.y;
#endif
}

// ---------------- sniff input dtypes (deterministic, same result every call)
__global__ void sniff_kernel(const u32* __restrict__ emb32,
                             const u32* __restrict__ mask32,
                             u32* __restrict__ flags) {
    if (threadIdx.x == 0) {
        u32 nz = 0;
        for (int i = 150; i < 300; ++i) nz |= emb32[i];
        flags[0] = (nz == 0) ? 1u : 0u;          // f32 floats?
        u32 m0 = mask32[0];
        flags[1] = ((m0 & 0xFFFFFF00u) != 0) ? 1u : 0u;  // bool mask?
    }
}

// ---------------- prep: normalize weights into canonical buffers
__global__ __launch_bounds__(256) void prep_kernel(
    const void* __restrict__ Wihf, const void* __restrict__ Wihb,
    const void* __restrict__ Whhf, const void* __restrict__ Whhb,
    const void* __restrict__ bihf, const void* __restrict__ bhhf,
    const void* __restrict__ bihb, const void* __restrict__ bhhb,
    const void* __restrict__ fcW, const void* __restrict__ fcb,
    const void* __restrict__ trans, const u32* __restrict__ flags,
    u16* __restrict__ Wpad, u32* __restrict__ Whh2, float* __restrict__ biasc,
    u16* __restrict__ fcWc, float* __restrict__ fcbf, float* __restrict__ transf) {
    const u32 isf32 = flags[0];
    int idx = blockIdx.x * 256 + threadIdx.x;
    if (idx < 2 * G_ * KP_) {
        int dir = idx / (G_ * KP_), rem = idx % (G_ * KP_);
        int g = rem / KP_, kp = rem % KP_;
        const void* src = dir ? Wihb : Wihf;
        float v = (kp < E_) ? loadf(src, (long)g * E_ + kp, isf32) : 0.f;
        Wpad[idx] = f2b(v);
        return;
    }
    idx -= 2 * G_ * KP_;
    if (idx < 2 * G_ * 64) {
        int dir = idx >> 15, rem = idx & 32767;
        int row = rem >> 6, k2 = rem & 63;
        const void* src = dir ? Whhb : Whhf;
        float w0 = loadf(src, (long)row * H_ + 2 * k2, isf32);
        float w1 = loadf(src, (long)row * H_ + 2 * k2 + 1, isf32);
        Whh2[idx] = (u32)f2h(w0) | ((u32)f2h(w1) << 16);
        return;
    }
    idx -= 2 * G_ * 64;
    if (idx < 2 * G_) {
        int dir = idx >> 9, g = idx & 511;
        biasc[idx] = loadf(dir ? bihb : bihf, g, isf32) +
                     loadf(dir ? bhhb : bhhf, g, isf32);
        return;
    }
    idx -= 2 * G_;
    if (idx < C_ * 256) { fcWc[idx] = f2b(loadf(fcW, idx, isf32)); return; }
    idx -= C_ * 256;
    if (idx < C_) { fcbf[idx] = loadf(fcb, idx, isf32); return; }
    idx -= C_;
    if (idx < C_ * C_) { transf[idx] = loadf(trans, idx, isf32); return; }
}

// ---------------- chunked xw GEMM with fused embedding gather (dtype-adaptive A).
// Epilogue interleaves columns: original gate index n -> ((n&127)<<2)|(n>>7)
// so the LSTM reads its 4 gates of unit j as one dwordx2 at column 4j.
__global__ __launch_bounds__(256) void gemm_xw(const int* __restrict__ x,
                                               const void* __restrict__ emb,
                                               const u16* __restrict__ Wpad,
                                               const float* __restrict__ biasc,
                                               const u32* __restrict__ flags,
                                               u16* __restrict__ xwf, u16* __restrict__ xwb,
                                               int tclog2, int t0f, int t0b) {
    const int m0 = blockIdx.x * 128;
    const int n0 = blockIdx.y * 128;
    const int dir = blockIdx.z;
    const u16* Bw = Wpad + (size_t)dir * G_ * KP_;
    u16* out = dir ? xwb : xwf;
    const int t0 = dir ? t0b : t0f;
    const int ts = dir ? -1 : 1;
    const int tcm = (1 << tclog2) - 1;
    const u32 isf32 = flags[0];

    __shared__ __align__(16) short As[128 * 32];
    __shared__ __align__(16) short Bs[128 * 32];
    __shared__ int xs[128];

    const int tid = threadIdx.x;
    const int lane = tid & 63;
    const int wave = tid >> 6;
    const int wm = wave & 1, wn = wave >> 1;
    const int lr = lane & 15, lq = lane >> 4;

    if (tid < 128) {
        int i = m0 + tid;
        int b = i >> tclog2;
        int r = i & tcm;
        xs[tid] = x[b * T_ + t0 + ts * r];
    }
    __syncthreads();

    f32x4 acc[4][4];
#pragma unroll
    for (int mt = 0; mt < 4; ++mt)
#pragma unroll
        for (int nt = 0; nt < 4; ++nt)
            acc[mt][nt] = (f32x4){0.f, 0.f, 0.f, 0.f};

    for (int kb = 0; kb < KP_; kb += 32) {
        if (isf32) {
            const float* ef = (const float*)emb;
#pragma unroll
            for (int hh = 0; hh < 4; ++hh) {
                int c = tid + hh * 256;
                int row = c >> 3;
                int k4 = (c & 7) * 4;
                int k = kb + k4;
                uint2 o = make_uint2(0u, 0u);
                if (k < E_) {
                    float4 v = *(const float4*)(ef + (size_t)xs[row] * E_ + k);
                    o.x = (u32)f2b(v.x) | ((u32)f2b(v.y) << 16);
                    o.y = (u32)f2b(v.z) | ((u32)f2b(v.w) << 16);
                }
                *(uint2*)(&As[row * 32 + k4]) = o;
            }
        } else {
            const u16* eb = (const u16*)emb;
#pragma unroll
            for (int hh = 0; hh < 4; ++hh) {
                int c = tid + hh * 256;
                int row = c >> 3;
                int k4 = (c & 7) * 4;
                int k = kb + k4;
                uint2 va = make_uint2(0u, 0u);
                if (k < E_)
                    va = *(const uint2*)(eb + (size_t)xs[row] * E_ + k);
                *(uint2*)(&As[row * 32 + k4]) = va;
            }
        }
#pragma unroll
        for (int hh = 0; hh < 2; ++hh) {
            int c = tid + hh * 256;
            int row = c >> 2;
            int k8 = (c & 3) * 8;
            uint4 vb = *(const uint4*)(Bw + (size_t)(n0 + row) * KP_ + kb + k8);
            *(uint4*)(&Bs[row * 32 + k8]) = vb;
        }
        __syncthreads();
        short8 afr[4], bfr[4];
#pragma unroll
        for (int mt = 0; mt < 4; ++mt)
            afr[mt] = *(const short8*)&As[(wm * 64 + mt * 16 + lr) * 32 + lq * 8];
#pragma unroll
        for (int nt = 0; nt < 4; ++nt)
            bfr[nt] = *(const short8*)&Bs[(wn * 64 + nt * 16 + lr) * 32 + lq * 8];
#pragma unroll
        for (int mt = 0; mt < 4; ++mt)
#pragma unroll
            for (int nt = 0; nt < 4; ++nt)
                acc[mt][nt] = __builtin_amdgcn_mfma_f32_16x16x32_bf16(afr[mt], bfr[nt], acc[mt][nt], 0, 0, 0);
        __syncthreads();
    }
#pragma unroll
    for (int nt = 0; nt < 4; ++nt) {
        int n = n0 + wn * 64 + nt * 16 + lr;
        float bn = biasc[dir * G_ + n];
        int np = ((n & 127) << 2) | (n >> 7);    // interleaved [unit][gate]
#pragma unroll
        for (int mt = 0; mt < 4; ++mt) {
            int mbase = m0 + wm * 64 + mt * 16 + lq * 4;
#pragma unroll
            for (int r = 0; r < 4; ++r)
                out[(size_t)(mbase + r) * G_ + np] = f2b(acc[mt][nt][r] + bn);
        }
    }
}

// ---------------- LSTM recurrence: one block per (b, dir), 256 threads (4 waves).
// K-SPLIT: thread (j = t>>1, kh = t&1) owns all 4 gates of unit j over k-half kh.
// W = 4 rows x 32 u32 = 128 VGPRs (fits r9-proven waves_per_eu(2,2)/256 budget,
// inline-asm loads). Each wave reads only its k-half of h: 8 ds_read_b128/step
// (vs 16 in r9) and 4 waves (vs 8) -> 4x less LDS-pipe pressure. Partial gate
// sums combined via __shfl_xor(.,1) (commutative-exact -> c replicated).
#define DOTQ4(acc, wq, hq) \
    acc = dot2f(wq.x, hq.x, acc); acc = dot2f(wq.y, hq.y, acc); \
    acc = dot2f(wq.z, hq.z, acc); acc = dot2f(wq.w, hq.w, acc);

#define GLD(dst, ptr, OFF) \
    asm volatile("global_load_dwordx4 %0, %1, off offset:" OFF : "=v"(dst) : "v"(ptr))

#define STEP_K(n) { uint4 hq = hp[n]; \
    DOTQ4(aI, wi##n, hq) DOTQ4(aF, wf##n, hq) \
    DOTQ4(aG, wg##n, hq) DOTQ4(aO, wo##n, hq) }

__global__ __launch_bounds__(256)
__attribute__((amdgpu_waves_per_eu(2, 2)))
void lstm_kernel(const u32* __restrict__ Whh2,
                 const u16* __restrict__ xwf,
                 const u16* __restrict__ xwb,
                 u16* __restrict__ hf,
                 u16* __restrict__ hb,
                 float* __restrict__ carry,
                 int TC, int t0f, int t0b, int first) {
    const int b = blockIdx.x;
    const int dir = blockIdx.y;
    const int t = threadIdx.x;
    const int j = t >> 1;                        // unit 0..127
    const int kh = t & 1;                        // k-half
    const u16* xw = (dir ? xwb : xwf) + (size_t)b * TC * G_ + 4 * j;
    u16* hout = (dir ? hb : hf) + (size_t)b * T_ * H_;
    const int t0 = dir ? t0b : t0f;
    const int ts = dir ? -1 : 1;
    float* carry_c = carry + (size_t)(dir * B_ + b) * H_;
    float* carry_h = carry + (size_t)(2 * B_ + dir * B_ + b) * H_;

    const u32* Wbase = Whh2 + (size_t)dir * G_ * 64 + (size_t)kh * 32;
    const uint4* WI = (const uint4*)(Wbase + (size_t)(0 + j) * 64);
    const uint4* WF = (const uint4*)(Wbase + (size_t)(128 + j) * 64);
    const uint4* WG = (const uint4*)(Wbase + (size_t)(256 + j) * 64);
    const uint4* WO = (const uint4*)(Wbase + (size_t)(384 + j) * 64);

    uint4 wi0, wi1, wi2, wi3, wi4, wi5, wi6, wi7;
    uint4 wf0, wf1, wf2, wf3, wf4, wf5, wf6, wf7;
    uint4 wg0, wg1, wg2, wg3, wg4, wg5, wg6, wg7;
    uint4 wo0, wo1, wo2, wo3, wo4, wo5, wo6, wo7;
    GLD(wi0, WI, "0");  GLD(wi1, WI, "16"); GLD(wi2, WI, "32");  GLD(wi3, WI, "48");
    GLD(wi4, WI, "64"); GLD(wi5, WI, "80"); GLD(wi6, WI, "96");  GLD(wi7, WI, "112");
    GLD(wf0, WF, "0");  GLD(wf1, WF, "16"); GLD(wf2, WF, "32");  GLD(wf3, WF, "48");
    GLD(wf4, WF, "64"); GLD(wf5, WF, "80"); GLD(wf6, WF, "96");  GLD(wf7, WF, "112");
    GLD(wg0, WG, "0");  GLD(wg1, WG, "16"); GLD(wg2, WG, "32");  GLD(wg3, WG, "48");
    GLD(wg4, WG, "64"); GLD(wg5, WG, "80"); GLD(wg6, WG, "96");  GLD(wg7, WG, "112");
    GLD(wo0, WO, "0");  GLD(wo1, WO, "16"); GLD(wo2, WO, "32");  GLD(wo3, WO, "48");
    GLD(wo4, WO, "64"); GLD(wo5, WO, "80"); GLD(wo6, WO, "96");  GLD(wo7, WO, "112");
    asm volatile("s_waitcnt vmcnt(0)" ::: "memory");

    __shared__ __align__(16) u16 hs2[2][H_];     // h as f16, 256 B per buffer

    float c0 = first ? 0.f : carry_c[j];
    if (kh == 0) hs2[0][j] = first ? (u16)0 : f2h(carry_h[j]);
    __syncthreads();

    int cur = 0;
    uint2 xq  = *(const uint2*)(xw);
    uint2 xq1 = (TC > 1) ? *(const uint2*)(xw + (size_t)1 * G_) : make_uint2(0u, 0u);
    float hlast = 0.f;
    for (int r = 0; r < TC; ++r) {
        uint2 xq2 = make_uint2(0u, 0u);
        if (r + 2 < TC) xq2 = *(const uint2*)(xw + (size_t)(r + 2) * G_);  // 2-deep prefetch
        const uint4* hp = (const uint4*)(&hs2[cur][kh * 64]);
        float aI = 0.f, aF = 0.f, aG = 0.f, aO = 0.f;
        STEP_K(0) STEP_K(1) STEP_K(2) STEP_K(3)
        STEP_K(4) STEP_K(5) STEP_K(6) STEP_K(7)
        // combine k-halves (xor-1 partner); commutative-exact -> replicated state
        aI += __shfl_xor(aI, 1, 64);
        aF += __shfl_xor(aF, 1, 64);
        aG += __shfl_xor(aG, 1, 64);
        aO += __shfl_xor(aO, 1, 64);
        float gi = sigmoidf_(b2f((u16)(xq.x & 0xffff)) + aI);
        float gf = sigmoidf_(b2f((u16)(xq.x >> 16)) + aF);
        float gg = tanhf_(b2f((u16)(xq.y & 0xffff)) + aG);
        float go = sigmoidf_(b2f((u16)(xq.y >> 16)) + aO);
        c0 = gf * c0 + gi * gg;
        float h = go * tanhf_(c0);
        hlast = h;
        if (kh == 0) {
            hs2[cur ^ 1][j] = f2h(h);
            hout[(size_t)(t0 + ts * r) * H_ + j] = f2b(h);
        }
        __syncthreads();
        cur ^= 1;
        xq = xq1; xq1 = xq2;
    }
    if (kh == 0) { carry_c[j] = c0; carry_h[j] = hlast; }
}

// ---------------- fc: logits = concat(hf,hb) @ fc_W^T + fc_b
__global__ __launch_bounds__(256) void fc_kernel(const u16* __restrict__ hf,
                                                 const u16* __restrict__ hb,
                                                 const u16* __restrict__ fcWc,
                                                 const float* __restrict__ fcbf,
                                                 const u32* __restrict__ flags,
                                                 float* __restrict__ logits,
                                                 void* __restrict__ dout) {
    __shared__ float Ws[C_ * 256];
    __shared__ float Hs[16 * 256];
    const int tid = threadIdx.x;
    const int bt0 = blockIdx.x * 64;
    const u32 isf32 = flags[0];
#pragma unroll
    for (int i = 0; i < C_; ++i) {
        int v = tid + i * 256;
        Ws[v] = b2f(fcWc[v]);
    }
    __syncthreads();
    for (int grp = 0; grp < 4; ++grp) {
        int btg = bt0 + grp * 16;
#pragma unroll
        for (int i = 0; i < 16; ++i) {
            int v = tid + i * 256;
            int r = v >> 8, k = v & 255;
            Hs[v] = (k < H_) ? b2f(hf[(size_t)(btg + r) * H_ + k])
                             : b2f(hb[(size_t)(btg + r) * H_ + (k - H_)]);
        }
        __syncthreads();
#pragma unroll
        for (int q = 0; q < 2; ++q) {
            int p = tid + q * 256;
            if (p < 16 * C_) {
                int r = p / C_, cc = p % C_;
                float acc = fcbf[cc];
                const float* wr = &Ws[cc * 256];
                const float* hr = &Hs[r * 256];
#pragma unroll
                for (int k = 0; k < 256; k += 4)
                    acc += wr[k] * hr[k] + wr[k + 1] * hr[k + 1] +
                           wr[k + 2] * hr[k + 2] + wr[k + 3] * hr[k + 3];
                size_t o = (size_t)(btg + r) * C_ + cc;
                logits[o] = acc;
                if (isf32) ((float*)dout)[1 + o] = acc;
                else       ((u16*)dout)[1 + o] = f2b(acc);
            }
        }
        __syncthreads();
    }
}

// ---------------- CRF phase A: per-(b,chunk) semiring product of step matrices.
__global__ __launch_bounds__(512) void crf_chunk(const float* __restrict__ logits,
                                                 const void* __restrict__ mask,
                                                 const float* __restrict__ transf,
                                                 const u32* __restrict__ flags,
                                                 float* __restrict__ Mc) {
    const int c = blockIdx.x;
    const int b = blockIdx.y;
    const int p = threadIdx.x;
    const bool act = p < C_ * C_;
    const int i = p / C_, j = p % C_;
    const u32 isbool = flags[1];

    __shared__ float P[C_ * C_];
    float trj[C_];
    if (act) {
#pragma unroll
        for (int k = 0; k < C_; ++k) trj[k] = transf[k * C_ + j];
        P[p] = (i == j) ? 0.f : -1e30f;
    }
    __syncthreads();

    const float* lg = logits + (size_t)b * T_ * C_;
    const int t0 = 1 + CS_ * c;

    float e = 0.f; int mk = 0;
    if (act) e = lg[(size_t)t0 * C_ + j];
    mk = loadmask(mask, b * T_ + t0, isbool);

    for (int s = 0; s < CS_; ++s) {
        int t = t0 + s;
        if (t >= T_) break;
        float e_n = 0.f; int mk_n = 0;
        int tn = t + 1;
        if (s + 1 < CS_ && tn < T_) {
            if (act) e_n = lg[(size_t)tn * C_ + j];
            mk_n = loadmask(mask, b * T_ + tn, isbool);
        }
        float nv = 0.f;
        if (act) {
            float sv[C_];
            float mx = -3e38f;
#pragma unroll
            for (int k = 0; k < C_; ++k) {
                sv[k] = P[i * C_ + k] + trj[k];
                mx = fmaxf(mx, sv[k]);
            }
            float sum = 0.f;
#pragma unroll
            for (int k = 0; k < C_; ++k) sum += __expf(sv[k] - mx);
            float la = mx + __logf(sum) + e;
            nv = mk ? la : P[p];
        }
        __syncthreads();
        if (act) P[p] = nv;
        __syncthreads();
        e = e_n; mk = mk_n;
    }
    if (act) Mc[((size_t)b * NCH_ + c) * (C_ * C_) + p] = P[p];
}

// ---------------- CRF phase B: per-b serial combine over 32 chunk matrices.
__global__ __launch_bounds__(64) void crf_combine(const float* __restrict__ logits,
                                                  const float* __restrict__ Mc,
                                                  float* __restrict__ log_den) {
    const int b = blockIdx.x;
    const int j = threadIdx.x;
    const bool act = j < C_;
    __shared__ float alpha[C_];
    const float* lg = logits + (size_t)b * T_ * C_;
    const float* mb = Mc + (size_t)b * NCH_ * (C_ * C_);
    if (act) alpha[j] = lg[j];
    __syncthreads();

    float mc[C_], mcn[C_];
    if (act) {
#pragma unroll
        for (int i = 0; i < C_; ++i) mc[i] = mb[i * C_ + j];
    }
    for (int c = 0; c < NCH_; ++c) {
        if (act && c + 1 < NCH_) {
#pragma unroll
            for (int i = 0; i < C_; ++i) mcn[i] = mb[(size_t)(c + 1) * (C_ * C_) + i * C_ + j];
        }
        float nv = 0.f;
        if (act) {
            float sv[C_];
            float mx = -3e38f;
#pragma unroll
            for (int i = 0; i < C_; ++i) {
                sv[i] = alpha[i] + mc[i];
                mx = fmaxf(mx, sv[i]);
            }
            float sum = 0.f;
#pragma unroll
            for (int i = 0; i < C_; ++i) sum += __expf(sv[i] - mx);
            nv = mx + __logf(sum);
        }
        __syncthreads();
        if (act) alpha[j] = nv;
        __syncthreads();
#pragma unroll
        for (int i = 0; i < C_; ++i) mc[i] = mcn[i];
    }
    if (j == 0) {
        float mx = -3e38f;
#pragma unroll
        for (int i = 0; i < C_; ++i) mx = fmaxf(mx, alpha[i]);
        float sum = 0.f;
#pragma unroll
        for (int i = 0; i < C_; ++i) sum += __expf(alpha[i] - mx);
        log_den[b] = mx + __logf(sum);
    }
}

// ---------------- loss numerator: one block per b, lane-strided over t
__global__ __launch_bounds__(64) void loss_partial(const float* __restrict__ logits,
                                                   const void* __restrict__ mask,
                                                   const int* __restrict__ tags,
                                                   const float* __restrict__ transf,
                                                   const u32* __restrict__ flags,
                                                   float* __restrict__ num) {
    const int b = blockIdx.x;
    const int lane = threadIdx.x;
    const u32 isbool = flags[1];
    const float* lg = logits + (size_t)b * T_ * C_;
    const int* tg = tags + b * T_;
    float s = 0.f;
    for (int t = lane; t < T_; t += 64) {
        int tt = tg[t];
        int mm = loadmask(mask, b * T_ + t, isbool);
        if (mm) s += lg[(size_t)t * C_ + tt];
        if (t >= 1) {
            int tp = tg[t - 1];
            int mp = loadmask(mask, b * T_ + t - 1, isbool);
            if (mm && mp) s += transf[tp * C_ + tt];
        }
    }
#pragma unroll
    for (int off = 32; off >= 1; off >>= 1)
        s += __shfl_down(s, off, 64);
    if (lane == 0) num[b] = s;
}

// ---------------- final: mean(log_den - log_num) -> dout[0]
__global__ __launch_bounds__(64) void loss_final(const float* __restrict__ den,
                                                 const float* __restrict__ num,
                                                 const u32* __restrict__ flags,
                                                 void* __restrict__ dout) {
    const int b = threadIdx.x;
    float v = den[b] - num[b];
#pragma unroll
    for (int off = 32; off >= 1; off >>= 1)
        v += __shfl_down(v, off, 64);
    if (b == 0) {
        float loss = v * (1.0f / B_);
        if (flags[0]) ((float*)dout)[0] = loss;
        else          ((u16*)dout)[0] = f2b(loss);
    }
}

extern "C" void kernel_launch(void* const* d_in, const int* in_sizes, int n_in,
                              void* d_out, int out_size, void* d_ws, size_t ws_size,
                              hipStream_t stream) {
    const int* x     = (const int*)d_in[0];
    const void* mask = d_in[1];
    const int* tags  = (const int*)d_in[2];
    const void* emb  = d_in[3];
    const void* Wihf = d_in[4];
    const void* Whhf = d_in[5];
    const void* bihf = d_in[6];
    const void* bhhf = d_in[7];
    const void* Wihb = d_in[8];
    const void* Whhb = d_in[9];
    const void* bihb = d_in[10];
    const void* bhhb = d_in[11];
    const void* fcW  = d_in[12];
    const void* fcb  = d_in[13];
    const void* trans= d_in[14];

    char* ws = (char*)d_ws;
    u32*   flags = (u32*)(ws + 0);                // 256
    u16*   Wpad  = (u16*)(ws + 256);              // 655,360
    u32*   Whh2  = (u32*)(ws + 655616);           // 262,144 (f16x2 packed)
    float* biasc = (float*)(ws + 917760);         // 4,096
    u16*   fcWc  = (u16*)(ws + 921856);           // 10,240
    float* fcbf  = (float*)(ws + 932096);         // 128
    float* transf= (float*)(ws + 932224);         // 1,664
    u16*   hf    = (u16*)(ws + 933888);           // 8,388,608
    u16*   hb    = (u16*)(ws + 9322496);          // 8,388,608
    float* lgf   = (float*)(ws + 17711104);       // 2,621,440
    float* den   = (float*)(ws + 20332544);       // 256
    float* carry = (float*)(ws + 20332800);       // 131,072
    float* Mc    = (float*)(ws + 20463872);       // 3,276,800
    float* numb  = (float*)(ws + 23740672);       // 256
    const size_t xw_off = 23740928;

    int TC, lg2;
    if (ws_size >= xw_off + 2ull * 65536ull * 512ull + 4096ull)      { TC = 512; lg2 = 9; }
    else if (ws_size >= xw_off + 2ull * 65536ull * 256ull + 4096ull) { TC = 256; lg2 = 8; }
    else if (ws_size >= xw_off + 2ull * 65536ull * 128ull + 4096ull) { TC = 128; lg2 = 7; }
    else if (ws_size >= xw_off + 2ull * 65536ull * 64ull + 4096ull)  { TC = 64;  lg2 = 6; }
    else                                                             { TC = 32;  lg2 = 5; }
    u16* xwf = (u16*)(ws + xw_off);
    u16* xwb = (u16*)(ws + xw_off + (size_t)65536 * TC);

    hipLaunchKernelGGL(sniff_kernel, dim3(1), dim3(64), 0, stream,
                       (const u32*)emb, (const u32*)mask, flags);
    hipLaunchKernelGGL(prep_kernel, dim3(1562), dim3(256), 0, stream,
                       Wihf, Wihb, Whhf, Whhb, bihf, bhhf, bihb, bhhb,
                       fcW, fcb, trans, flags, Wpad, Whh2, biasc, fcWc, fcbf, transf);

    const int nc = T_ / TC;
    for (int ci = 0; ci < nc; ++ci) {
        int t0f = ci * TC;
        int t0b = T_ - 1 - ci * TC;
        hipLaunchKernelGGL(gemm_xw, dim3((B_ * TC) / 128, 4, 2), dim3(256), 0, stream,
                           x, emb, Wpad, biasc, flags, xwf, xwb, lg2, t0f, t0b);
        hipLaunchKernelGGL(lstm_kernel, dim3(B_, 2), dim3(256), 0, stream,
                           Whh2, xwf, xwb, hf, hb, carry, TC, t0f, t0b, (ci == 0) ? 1 : 0);
    }

    hipLaunchKernelGGL(fc_kernel, dim3(512), dim3(256), 0, stream,
                       hf, hb, fcWc, fcbf, flags, lgf, d_out);
    hipLaunchKernelGGL(crf_chunk, dim3(NCH_, B_), dim3(512), 0, stream,
                       lgf, mask, transf, flags, Mc);
    hipLaunchKernelGGL(crf_combine, dim3(B_), dim3(64), 0, stream, lgf, Mc, den);
    hipLaunchKernelGGL(loss_partial, dim3(B_), dim3(64), 0, stream,
                       lgf, mask, tags, transf, flags, numb);
    hipLaunchKernelGGL(loss_final, dim3(1), dim3(64), 0, stream, den, numb, flags, d_out);
}